// Round 1
// baseline (415.196 us; speedup 1.0000x reference)
//
#include <hip/hip_runtime.h>

#define S_LEN 4096
#define LOG2S 12
#define NT 256
#define PER (S_LEN / NT)        // 16 elements per thread
#define NBF (S_LEN / (2 * NT))  // 8 butterflies per thread per stage
#define RANK 8

__global__ __launch_bounds__(NT) void recip_mixer(
    const float* __restrict__ x,
    const float* __restrict__ Ur, const float* __restrict__ Ui,
    const float* __restrict__ Vr, const float* __restrict__ Vi,
    const float* __restrict__ Wr, const float* __restrict__ Wi,
    const float* __restrict__ P1w, const float* __restrict__ P1b,
    const float* __restrict__ P2w, const float* __restrict__ P2b,
    const float* __restrict__ alphap,
    float* __restrict__ out)
{
    __shared__ float re[S_LEN], im[S_LEN];
    __shared__ float twr[S_LEN / 2], twi[S_LEN / 2];
    __shared__ float red[128];
    __shared__ float hid[RANK];
    __shared__ float gam[2 * RANK];

    const int tid  = threadIdx.x;
    const int row  = blockIdx.x;
    const int lane = tid & 63;
    const int wid  = tid >> 6;

    // ---- twiddle table: twr/twi[j] = exp(-2*pi*i*j/S), j in [0, S/2)
    const float w0 = -6.28318530717958647692f / (float)S_LEN;
    for (int j = tid; j < S_LEN / 2; j += NT) {
        float sn, cs;
        __sincosf(w0 * (float)j, &sn, &cs);
        twr[j] = cs;
        twi[j] = sn;
    }

    // ---- load row with bit-reversed LDS placement (forward DIT wants this)
    const float* xrow = x + (size_t)row * S_LEN;
#pragma unroll
    for (int i = 0; i < PER; i++) {
        int idx = tid + NT * i;
        int pos = (int)(__brev((unsigned)idx) >> (32 - LOG2S));
        re[pos] = xrow[idx];
        im[pos] = 0.0f;
    }
    __syncthreads();

    // ---- forward FFT: radix-2 DIT, 12 stages, natural-order output
    for (int s = 1; s <= LOG2S; s++) {
        const int half  = 1 << (s - 1);
        const int shift = LOG2S - s;
#pragma unroll
        for (int i = 0; i < NBF; i++) {
            int b  = tid + NT * i;
            int j  = b & (half - 1);
            int i0 = ((b >> (s - 1)) << s) + j;
            int i1 = i0 + half;
            float c  = twr[j << shift];
            float sn = twi[j << shift];
            float xr = re[i1], xi = im[i1];
            float tr = c * xr - sn * xi;
            float ti = c * xi + sn * xr;
            float ar = re[i0], ai = im[i0];
            re[i1] = ar - tr; im[i1] = ai - ti;
            re[i0] = ar + tr; im[i0] = ai + ti;
        }
        __syncthreads();
    }

    // ---- phase 1: hidden = relu(P1w @ [Re z ; Im z] + P1b)  (rank-8 reduction)
    {
        float h[RANK];
#pragma unroll
        for (int r = 0; r < RANK; r++) h[r] = 0.0f;
        for (int i = 0; i < PER; i++) {
            int k = tid + NT * i;
            float zr = re[k], zi = im[k];
#pragma unroll
            for (int r = 0; r < RANK; r++) {
                h[r] += zr * P1w[r * (2 * S_LEN) + k]
                      + zi * P1w[r * (2 * S_LEN) + S_LEN + k];
            }
        }
#pragma unroll
        for (int r = 0; r < RANK; r++) {
#pragma unroll
            for (int off = 32; off > 0; off >>= 1)
                h[r] += __shfl_xor(h[r], off, 64);
        }
        if (lane == 0) {
#pragma unroll
            for (int r = 0; r < RANK; r++) red[wid * RANK + r] = h[r];
        }
        __syncthreads();
        if (tid < RANK) {
            float v = red[tid] + red[RANK + tid] + red[2 * RANK + tid] + red[3 * RANK + tid];
            hid[tid] = fmaxf(v + P1b[tid], 0.0f);
        }
        __syncthreads();
    }

    // ---- phase 2+3 merged: per-k gain (base + interpolated delta), scale z,
    //      and accumulate p = z@U^T, q = z@V^T partials in the same pass.
    {
        float hh[RANK];
#pragma unroll
        for (int r = 0; r < RANK; r++) hh[r] = hid[r];
        const float alpha = alphap[0];

        float pr[RANK], pim[RANK], qr[RANK], qim[RANK];
#pragma unroll
        for (int r = 0; r < RANK; r++) { pr[r] = 0.f; pim[r] = 0.f; qr[r] = 0.f; qim[r] = 0.f; }

        for (int i = 0; i < PER; i++) {
            int k = tid + NT * i;
            int m = (k < S_LEN - k) ? k : (S_LEN - k);   // min(k, S-k)
            float nf = (float)(2 * m) * (1.0f / (float)S_LEN);
            float t  = nf * 5.0f;                         // nf / 0.2
            float lb = __expf(-0.5f * t * t);
            float hd = 0.5f / (1.0f + __expf(-(nf - 0.6f) * 10.0f)); // tw = 0.1
            float bg = fmaxf(1.0f + lb - hd, 0.0f);

            float scaled = nf * 4095.0f;
            float fl  = floorf(scaled);
            int   lo  = (int)fl;
            int   hi  = (int)ceilf(scaled);
            float fr  = scaled - fl;

            const float4* p2lo = (const float4*)(P2w + (size_t)lo * RANK);
            const float4* p2hi = (const float4*)(P2w + (size_t)hi * RANK);
            float4 a0 = p2lo[0], a1 = p2lo[1];
            float4 b0 = p2hi[0], b1 = p2hi[1];
            float dlo = P2b[lo]
                      + hh[0] * a0.x + hh[1] * a0.y + hh[2] * a0.z + hh[3] * a0.w
                      + hh[4] * a1.x + hh[5] * a1.y + hh[6] * a1.z + hh[7] * a1.w;
            float dhi = P2b[hi]
                      + hh[0] * b0.x + hh[1] * b0.y + hh[2] * b0.z + hh[3] * b0.w
                      + hh[4] * b1.x + hh[5] * b1.y + hh[6] * b1.z + hh[7] * b1.w;
            float di = dlo + (dhi - dlo) * fr;
            float g  = fmaxf(bg + alpha * di, 0.0f);

            float zr = re[k] * g;
            float zi = im[k] * g;
            re[k] = zr;
            im[k] = zi;

#pragma unroll
            for (int r = 0; r < RANK; r++) {
                float ur = Ur[r * S_LEN + k], ui = Ui[r * S_LEN + k];
                pr[r]  += zr * ur - zi * ui;
                pim[r] += zr * ui + zi * ur;
                float vr = Vr[r * S_LEN + k], vi = Vi[r * S_LEN + k];
                qr[r]  += zr * vr - zi * vi;
                qim[r] += zr * vi + zi * vr;
            }
        }

        // block-reduce the 32 partials
#pragma unroll
        for (int r = 0; r < RANK; r++) {
#pragma unroll
            for (int off = 32; off > 0; off >>= 1) {
                pr[r]  += __shfl_xor(pr[r],  off, 64);
                pim[r] += __shfl_xor(pim[r], off, 64);
                qr[r]  += __shfl_xor(qr[r],  off, 64);
                qim[r] += __shfl_xor(qim[r], off, 64);
            }
        }
        if (lane == 0) {
#pragma unroll
            for (int r = 0; r < RANK; r++) {
                red[wid * 32 + r]      = pr[r];
                red[wid * 32 + 8 + r]  = pim[r];
                red[wid * 32 + 16 + r] = qr[r];
                red[wid * 32 + 24 + r] = qim[r];
            }
        }
        __syncthreads();
        if (tid < 32) {
            float v = red[tid] + red[32 + tid] + red[64 + tid] + red[96 + tid];
            red[tid] = v;   // each lane touches only its own slot: safe
        }
        __syncthreads();
        if (tid < RANK) {
            float prr = red[tid],      pii = red[8 + tid];
            float qrr = red[16 + tid], qii = red[24 + tid];
            gam[tid]        = prr * qrr + pii * qii;  // Re(p * conj(q))
            gam[RANK + tid] = pii * qrr - prr * qii;  // Im(p * conj(q))
        }
        __syncthreads();
    }

    // ---- phase 4: z[k] += sum_r gamma[r] * (Wr[k,r] + i*Wi[k,r])
    {
        float gr[RANK], gi[RANK];
#pragma unroll
        for (int r = 0; r < RANK; r++) { gr[r] = gam[r]; gi[r] = gam[RANK + r]; }
        const float4* Wr4 = (const float4*)Wr;
        const float4* Wi4 = (const float4*)Wi;
        for (int i = 0; i < PER; i++) {
            int k = tid + NT * i;
            float4 wa = Wr4[k * 2], wb = Wr4[k * 2 + 1];
            float4 va = Wi4[k * 2], vb = Wi4[k * 2 + 1];
            float wr[RANK] = { wa.x, wa.y, wa.z, wa.w, wb.x, wb.y, wb.z, wb.w };
            float wi[RANK] = { va.x, va.y, va.z, va.w, vb.x, vb.y, vb.z, vb.w };
            float ar = 0.f, ai = 0.f;
#pragma unroll
            for (int r = 0; r < RANK; r++) {
                ar += gr[r] * wr[r] - gi[r] * wi[r];
                ai += gr[r] * wi[r] + gi[r] * wr[r];
            }
            re[k] += ar;
            im[k] += ai;
        }
        __syncthreads();
    }

    // ---- inverse FFT: radix-2 DIF with conjugated twiddles (sign +),
    //      natural-order input, bit-reversed output (fixed at store time)
    for (int s = LOG2S; s >= 1; s--) {
        const int half  = 1 << (s - 1);
        const int shift = LOG2S - s;
#pragma unroll
        for (int i = 0; i < NBF; i++) {
            int b  = tid + NT * i;
            int j  = b & (half - 1);
            int i0 = ((b >> (s - 1)) << s) + j;
            int i1 = i0 + half;
            float c  = twr[j << shift];
            float sn = -twi[j << shift];   // conj -> exp(+2*pi*i*j/len)
            float ar = re[i0], ai = im[i0];
            float br = re[i1], bi = im[i1];
            re[i0] = ar + br;
            im[i0] = ai + bi;
            float dr = ar - br, di2 = ai - bi;
            re[i1] = c * dr - sn * di2;
            im[i1] = c * di2 + sn * dr;
        }
        __syncthreads();
    }

    // ---- store real part (bit-reversed gather from LDS, coalesced global write)
    float* orow = out + (size_t)row * S_LEN;
    const float scale = 1.0f / (float)S_LEN;
#pragma unroll
    for (int i = 0; i < PER; i++) {
        int idx = tid + NT * i;
        int pos = (int)(__brev((unsigned)idx) >> (32 - LOG2S));
        orow[idx] = re[pos] * scale;
    }
}

extern "C" void kernel_launch(void* const* d_in, const int* in_sizes, int n_in,
                              void* d_out, int out_size, void* d_ws, size_t ws_size,
                              hipStream_t stream) {
    const float* x    = (const float*)d_in[0];
    const float* Ur   = (const float*)d_in[1];
    const float* Ui   = (const float*)d_in[2];
    const float* Vr   = (const float*)d_in[3];
    const float* Vi   = (const float*)d_in[4];
    const float* Wr   = (const float*)d_in[5];
    const float* Wi   = (const float*)d_in[6];
    const float* P1w  = (const float*)d_in[7];
    const float* P1b  = (const float*)d_in[8];
    const float* P2w  = (const float*)d_in[9];
    const float* P2b  = (const float*)d_in[10];
    const float* alph = (const float*)d_in[11];

    recip_mixer<<<dim3(2048), dim3(NT), 0, stream>>>(
        x, Ur, Ui, Vr, Vi, Wr, Wi, P1w, P1b, P2w, P2b, alph, (float*)d_out);
}

// Round 2
// 245.451 us; speedup vs baseline: 1.6916x; 1.6916x over previous
//
#include <hip/hip_runtime.h>

#define S_LEN 4096
#define NT 256
#define PER 16
#define RANK 8
#define AP 4352   // padded LDS array size (transpose-2 max addr 4350)

__device__ __forceinline__ void cmul(float& xr, float& xi, float cr, float ci){
    float tr = xr*cr - xi*ci;
    xi = xr*ci + xi*cr;
    xr = tr;
}

// 4-point DFT, in place. SIGN=-1 forward (W=e^{-i}), SIGN=+1 inverse.
template<int SIGN>
__device__ __forceinline__ void dft4(float& ar,float& ai,float& br,float& bi,
                                     float& cr,float& ci,float& dr,float& di){
    float Ar=ar+cr, Ai=ai+ci;
    float Br=ar-cr, Bi=ai-ci;
    float Cr=br+dr, Ci=bi+di;
    float Dr, Di;
    if (SIGN < 0){ Dr = bi-di; Di = dr-br; }   // -i*(b-d)
    else         { Dr = di-bi; Di = br-dr; }   // +i*(b-d)
    ar=Ar+Cr; ai=Ai+Ci;
    br=Br+Dr; bi=Bi+Di;
    cr=Ar-Cr; ci=Ai-Ci;
    dr=Br-Dr; di=Bi-Di;
}

// 16-point DFT in registers (2 radix-4 stages).
// Input: u[0..15] natural order. Output: X[j+4q] sits at slot 4*j+q,
// i.e. X[k] is at slot 4*(k&3)+(k>>2).
template<int SIGN>
__device__ __forceinline__ void dft16(float ur[16], float ui[16]){
    constexpr float TC[10] = {1.0f, 0.92387953251128674f, 0.70710678118654752f,
                              0.38268343236508977f, 0.0f, -0.38268343236508977f,
                              -0.70710678118654752f, -0.92387953251128674f, -1.0f,
                              -0.92387953251128674f};
    constexpr float TS[10] = {0.0f, 0.38268343236508977f, 0.70710678118654752f,
                              0.92387953251128674f, 1.0f, 0.92387953251128674f,
                              0.70710678118654752f, 0.38268343236508977f, 0.0f,
                              -0.38268343236508977f};
    // stage 1: E_p = DFT4 of decimated subsequence (u_p, u_{p+4}, u_{p+8}, u_{p+12});
    // E_p[j] lands at slot p+4j
#pragma unroll
    for (int p=0;p<4;p++)
        dft4<SIGN>(ur[p],ui[p], ur[p+4],ui[p+4], ur[p+8],ui[p+8], ur[p+12],ui[p+12]);
    // stage 2 twiddles: slot 4j+p *= W16^{p*j}
#pragma unroll
    for (int j=1;j<4;j++){
#pragma unroll
        for (int p=1;p<4;p++){
            const int e = p*j;
            const float c = TC[e];
            const float s = (SIGN < 0) ? -TS[e] : TS[e];
            cmul(ur[4*j+p], ui[4*j+p], c, s);
        }
    }
    // stage 2 butterflies over p for each j
#pragma unroll
    for (int j=0;j<4;j++)
        dft4<SIGN>(ur[4*j+0],ui[4*j+0], ur[4*j+1],ui[4*j+1],
                   ur[4*j+2],ui[4*j+2], ur[4*j+3],ui[4*j+3]);
}

// multiply u[m] by exp(SIGN * i * theta * m), m = 0..15 (iterative powers)
template<int SIGN>
__device__ __forceinline__ void twiddle_powers(float ur[16], float ui[16], float theta){
    float s, c;
    __sincosf(theta, &s, &c);
    const float wi = (SIGN < 0) ? -s : s;
    const float wr = c;
    float pr = wr, pi = wi;      // w^1
    cmul(ur[1], ui[1], pr, pi);
#pragma unroll
    for (int m=2;m<16;m++){
        float nr = pr*wr - pi*wi;
        pi = pr*wi + pi*wr;
        pr = nr;
        cmul(ur[m], ui[m], pr, pi);
    }
}

__global__ __launch_bounds__(NT, 4) void recip_mixer(
    const float* __restrict__ x,
    const float* __restrict__ Ur, const float* __restrict__ Ui,
    const float* __restrict__ Vr, const float* __restrict__ Vi,
    const float* __restrict__ Wr, const float* __restrict__ Wi,
    const float* __restrict__ P1w, const float* __restrict__ P1b,
    const float* __restrict__ P2w, const float* __restrict__ P2b,
    const float* __restrict__ alphap,
    float* __restrict__ out)
{
    __shared__ float sre[AP], sim[AP];
    __shared__ float red[128];
    __shared__ float hid[RANK];
    __shared__ float gam[2 * RANK];

    const int t    = threadIdx.x;
    const int row  = blockIdx.x;
    const int lane = t & 63;
    const int wid  = t >> 6;

    float ur[16], ui[16];

    // ================= forward FFT: natural in -> natural k out =================
    // decomposition n = n1 + 16*n1' + 256*n2';  k = (k2' + 16*k1') + 256*k1
    {
        // round 1: thread (n1=t&15, n1'=t>>4) DFTs over n2' (reads x[t+256c], coalesced)
        const float* xrow = x + (size_t)row * S_LEN;
#pragma unroll
        for (int c=0;c<16;c++){ ur[c] = xrow[t + 256*c]; ui[c] = 0.0f; }
        dft16<-1>(ur, ui);
        // write A[n1][n1'][k2'] at n1 + 272*n1' + 16*k2'  (banks: 2-way, free)
        const int base1 = (t & 15) + 272 * (t >> 4);
#pragma unroll
        for (int k=0;k<16;k++){
            const int slot = 4*(k&3) + (k>>2);
            sre[base1 + 16*k] = ur[slot];
            sim[base1 + 16*k] = ui[slot];
        }
    }
    __syncthreads();
    {
        // round 2: thread (n1=t&15, k2'=t>>4): read A over n1', twiddle W_256^{n1'k2'}, DFT
        const int n1 = t & 15, k2p = t >> 4;
#pragma unroll
        for (int m=0;m<16;m++){
            ur[m] = sre[n1 + 272*m + 16*k2p];
            ui[m] = sim[n1 + 272*m + 16*k2p];
        }
        twiddle_powers<-1>(ur, ui, 6.2831853071795864769f * (float)k2p * (1.0f/256.0f));
        dft16<-1>(ur, ui);
        __syncthreads();   // all of A consumed before overwriting with B
        // write B[n1][k1'][k2'] at k2' + 17*n1 + 272*k1'
        const int base2 = k2p + 17*n1;
#pragma unroll
        for (int k=0;k<16;k++){
            const int slot = 4*(k&3) + (k>>2);
            sre[base2 + 272*k] = ur[slot];
            sim[base2 + 272*k] = ui[slot];
        }
    }
    __syncthreads();
    {
        // round 3: thread k2 = t (k2'=t&15, k1'=t>>4): read B over n1, twiddle W_4096^{n1 k2}, DFT
#pragma unroll
        for (int m=0;m<16;m++){
            ur[m] = sre[(t&15) + 17*m + 272*(t>>4)];
            ui[m] = sim[(t&15) + 17*m + 272*(t>>4)];
        }
        twiddle_powers<-1>(ur, ui, 6.2831853071795864769f * (float)t * (1.0f/4096.0f));
        dft16<-1>(ur, ui);
        __syncthreads();   // B consumed before overwriting with linear spectrum
        // write spectrum linear: z[k2 + 256*k1] (consecutive lanes -> free)
#pragma unroll
        for (int k=0;k<16;k++){
            const int slot = 4*(k&3) + (k>>2);
            sre[t + 256*k] = ur[slot];
            sim[t + 256*k] = ui[slot];
        }
    }
    __syncthreads();

    // ================= middle phase (unchanged logic, z in sre/sim linear) =====
    // phase 1: hidden = relu(P1w @ [Re z ; Im z] + P1b)
    {
        float h[RANK];
#pragma unroll
        for (int r = 0; r < RANK; r++) h[r] = 0.0f;
        for (int i = 0; i < PER; i++) {
            int k = t + NT * i;
            float zr = sre[k], zi = sim[k];
#pragma unroll
            for (int r = 0; r < RANK; r++) {
                h[r] += zr * P1w[r * (2 * S_LEN) + k]
                      + zi * P1w[r * (2 * S_LEN) + S_LEN + k];
            }
        }
#pragma unroll
        for (int r = 0; r < RANK; r++) {
#pragma unroll
            for (int off = 32; off > 0; off >>= 1)
                h[r] += __shfl_xor(h[r], off, 64);
        }
        if (lane == 0) {
#pragma unroll
            for (int r = 0; r < RANK; r++) red[wid * RANK + r] = h[r];
        }
        __syncthreads();
        if (t < RANK) {
            float v = red[t] + red[RANK + t] + red[2 * RANK + t] + red[3 * RANK + t];
            hid[t] = fmaxf(v + P1b[t], 0.0f);
        }
        __syncthreads();
    }

    // phase 2+3: per-k gain, scale z, accumulate p/q rank-8 partials
    {
        float hh[RANK];
#pragma unroll
        for (int r = 0; r < RANK; r++) hh[r] = hid[r];
        const float alpha = alphap[0];

        float pr[RANK], pim[RANK], qr[RANK], qim[RANK];
#pragma unroll
        for (int r = 0; r < RANK; r++) { pr[r]=0.f; pim[r]=0.f; qr[r]=0.f; qim[r]=0.f; }

        for (int i = 0; i < PER; i++) {
            int k = t + NT * i;
            int m = (k < S_LEN - k) ? k : (S_LEN - k);
            float nf = (float)(2 * m) * (1.0f / (float)S_LEN);
            float tt = nf * 5.0f;
            float lb = __expf(-0.5f * tt * tt);
            float hd = 0.5f / (1.0f + __expf(-(nf - 0.6f) * 10.0f));
            float bg = fmaxf(1.0f + lb - hd, 0.0f);

            float scaled = nf * 4095.0f;
            float fl  = floorf(scaled);
            int   lo  = (int)fl;
            int   hi  = (int)ceilf(scaled);
            float fr  = scaled - fl;

            const float4* p2lo = (const float4*)(P2w + (size_t)lo * RANK);
            const float4* p2hi = (const float4*)(P2w + (size_t)hi * RANK);
            float4 a0 = p2lo[0], a1 = p2lo[1];
            float4 b0 = p2hi[0], b1 = p2hi[1];
            float dlo = P2b[lo]
                      + hh[0]*a0.x + hh[1]*a0.y + hh[2]*a0.z + hh[3]*a0.w
                      + hh[4]*a1.x + hh[5]*a1.y + hh[6]*a1.z + hh[7]*a1.w;
            float dhi = P2b[hi]
                      + hh[0]*b0.x + hh[1]*b0.y + hh[2]*b0.z + hh[3]*b0.w
                      + hh[4]*b1.x + hh[5]*b1.y + hh[6]*b1.z + hh[7]*b1.w;
            float di = dlo + (dhi - dlo) * fr;
            float g  = fmaxf(bg + alpha * di, 0.0f);

            float zr = sre[k] * g;
            float zi = sim[k] * g;
            sre[k] = zr;
            sim[k] = zi;

#pragma unroll
            for (int r = 0; r < RANK; r++) {
                float u_ = Ur[r * S_LEN + k], v_ = Ui[r * S_LEN + k];
                pr[r]  += zr * u_ - zi * v_;
                pim[r] += zr * v_ + zi * u_;
                float w_ = Vr[r * S_LEN + k], y_ = Vi[r * S_LEN + k];
                qr[r]  += zr * w_ - zi * y_;
                qim[r] += zr * y_ + zi * w_;
            }
        }

#pragma unroll
        for (int r = 0; r < RANK; r++) {
#pragma unroll
            for (int off = 32; off > 0; off >>= 1) {
                pr[r]  += __shfl_xor(pr[r],  off, 64);
                pim[r] += __shfl_xor(pim[r], off, 64);
                qr[r]  += __shfl_xor(qr[r],  off, 64);
                qim[r] += __shfl_xor(qim[r], off, 64);
            }
        }
        if (lane == 0) {
#pragma unroll
            for (int r = 0; r < RANK; r++) {
                red[wid * 32 + r]      = pr[r];
                red[wid * 32 + 8 + r]  = pim[r];
                red[wid * 32 + 16 + r] = qr[r];
                red[wid * 32 + 24 + r] = qim[r];
            }
        }
        __syncthreads();
        if (t < 32) {
            float v = red[t] + red[32 + t] + red[64 + t] + red[96 + t];
            red[t] = v;
        }
        __syncthreads();
        if (t < RANK) {
            float prr = red[t],      pii = red[8 + t];
            float qrr = red[16 + t], qii = red[24 + t];
            gam[t]        = prr * qrr + pii * qii;  // Re(p * conj(q))
            gam[RANK + t] = pii * qrr - prr * qii;  // Im(p * conj(q))
        }
        __syncthreads();
    }

    // phase 4: z[k] += sum_r gamma[r] * (Wr[k,r] + i*Wi[k,r])
    {
        float gr[RANK], gi[RANK];
#pragma unroll
        for (int r = 0; r < RANK; r++) { gr[r] = gam[r]; gi[r] = gam[RANK + r]; }
        const float4* Wr4 = (const float4*)Wr;
        const float4* Wi4 = (const float4*)Wi;
        for (int i = 0; i < PER; i++) {
            int k = t + NT * i;
            float4 wa = Wr4[k * 2], wb = Wr4[k * 2 + 1];
            float4 va = Wi4[k * 2], vb = Wi4[k * 2 + 1];
            float wr_[RANK] = { wa.x, wa.y, wa.z, wa.w, wb.x, wb.y, wb.z, wb.w };
            float wi_[RANK] = { va.x, va.y, va.z, va.w, vb.x, vb.y, vb.z, vb.w };
            float ar = 0.f, ai = 0.f;
#pragma unroll
            for (int r = 0; r < RANK; r++) {
                ar += gr[r] * wr_[r] - gi[r] * wi_[r];
                ai += gr[r] * wi_[r] + gi[r] * wr_[r];
            }
            sre[k] += ar;
            sim[k] += ai;
        }
        __syncthreads();
    }

    // ================= inverse FFT: natural k in -> natural n out ==============
    {
        // round 1: read z linear (own slots), DFT over high digit
#pragma unroll
        for (int c=0;c<16;c++){ ur[c] = sre[t + 256*c]; ui[c] = sim[t + 256*c]; }
        dft16<1>(ur, ui);
        __syncthreads();   // everyone done reading z before A overwrites it
        const int base1 = (t & 15) + 272 * (t >> 4);
#pragma unroll
        for (int k=0;k<16;k++){
            const int slot = 4*(k&3) + (k>>2);
            sre[base1 + 16*k] = ur[slot];
            sim[base1 + 16*k] = ui[slot];
        }
    }
    __syncthreads();
    {
        const int a = t & 15, b = t >> 4;
#pragma unroll
        for (int m=0;m<16;m++){
            ur[m] = sre[a + 272*m + 16*b];
            ui[m] = sim[a + 272*m + 16*b];
        }
        twiddle_powers<1>(ur, ui, 6.2831853071795864769f * (float)b * (1.0f/256.0f));
        dft16<1>(ur, ui);
        __syncthreads();
        const int base2 = b + 17*a;
#pragma unroll
        for (int k=0;k<16;k++){
            const int slot = 4*(k&3) + (k>>2);
            sre[base2 + 272*k] = ur[slot];
            sim[base2 + 272*k] = ui[slot];
        }
    }
    __syncthreads();
    {
#pragma unroll
        for (int m=0;m<16;m++){
            ur[m] = sre[(t&15) + 17*m + 272*(t>>4)];
            ui[m] = sim[(t&15) + 17*m + 272*(t>>4)];
        }
        twiddle_powers<1>(ur, ui, 6.2831853071795864769f * (float)t * (1.0f/4096.0f));
        dft16<1>(ur, ui);
        // write real part straight to global: out[n], n = t + 256*m1 (coalesced)
        float* orow = out + (size_t)row * S_LEN;
        const float scale = 1.0f / (float)S_LEN;
#pragma unroll
        for (int k=0;k<16;k++){
            const int slot = 4*(k&3) + (k>>2);
            orow[t + 256*k] = ur[slot] * scale;
        }
    }
}

extern "C" void kernel_launch(void* const* d_in, const int* in_sizes, int n_in,
                              void* d_out, int out_size, void* d_ws, size_t ws_size,
                              hipStream_t stream) {
    const float* x    = (const float*)d_in[0];
    const float* Ur   = (const float*)d_in[1];
    const float* Ui   = (const float*)d_in[2];
    const float* Vr   = (const float*)d_in[3];
    const float* Vi   = (const float*)d_in[4];
    const float* Wr   = (const float*)d_in[5];
    const float* Wi   = (const float*)d_in[6];
    const float* P1w  = (const float*)d_in[7];
    const float* P1b  = (const float*)d_in[8];
    const float* P2w  = (const float*)d_in[9];
    const float* P2b  = (const float*)d_in[10];
    const float* alph = (const float*)d_in[11];

    recip_mixer<<<dim3(2048), dim3(NT), 0, stream>>>(
        x, Ur, Ui, Vr, Vi, Wr, Wi, P1w, P1b, P2w, P2b, alph, (float*)d_out);
}